// Round 1
// baseline (99.866 us; speedup 1.0000x reference)
//
#include <hip/hip_runtime.h>

#define D 768
#define B 512

// Kernel 1 tiling
#define BTILE 64     // batch rows per block
#define JTILE 128    // j columns per block
#define IC 32        // i-chunk staged in LDS
#define ISPLIT 8     // split of the i dimension across blocks
#define ILEN (D / ISPLIT)   // 96 i's per block

// logits[b][k] += sum_{i in slice, j in tile} v[b,i] * W_k[i,j] * s[b,j]
__global__ __launch_bounds__(256, 2)
void logits_kernel(const float* __restrict__ v_x,
                   const float* __restrict__ s_x,
                   const float* __restrict__ fc_w,
                   float* __restrict__ logits /* [B][2], pre-zeroed */)
{
    __shared__ float vT[IC][BTILE + 4];    // [i][b]  transposed v tile
    __shared__ float wS[IC][JTILE + 4];    // [i][j]  W tile

    const int tid = threadIdx.x;
    const int j0  = blockIdx.x * JTILE;
    const int b0  = blockIdx.y * BTILE;
    const int kz  = blockIdx.z;            // 0..2*ISPLIT-1
    const int k   = kz >> 3;               // 0..1
    const int isp = kz & (ISPLIT - 1);
    const int ibase = isp * ILEN;

    // wave-structured 8x8 lane map: lanes 0..7 = jt (fast), bits 3..5 = bt
    const int w    = tid >> 6;             // wave 0..3
    const int lane = tid & 63;
    const int jt   = lane & 7;             // 0..7
    const int bt   = (lane >> 3) & 7;      // 0..7
    const int bo   = (w >> 1) * 32;        // which b-half of the tile
    const int jo   = (w & 1) * 64;         // which j-half of the tile

    const int bb = bo + bt * 4;            // thread's base b within tile (owns 4 rows)
    const int jj = jo + jt * 8;            // thread's base j within tile (owns 8 cols)

    float acc[4][8];
#pragma unroll
    for (int m = 0; m < 4; ++m)
#pragma unroll
        for (int n = 0; n < 8; ++n) acc[m][n] = 0.f;

    const float* __restrict__ Wk = fc_w + (size_t)k * D * D;

    for (int ch = 0; ch < ILEN / IC; ++ch) {
        const int ic = ibase + ch * IC;

        // stage W tile: wS[r][c] = W_k[ic+r][j0+c]  (32x128 floats, 1024 float4)
#pragma unroll
        for (int p = 0; p < 4; ++p) {
            int q  = tid + 256 * p;        // 0..1023
            int r  = q >> 5;               // 0..31
            int c4 = q & 31;               // 0..31
            float4 t = *reinterpret_cast<const float4*>(
                &Wk[(size_t)(ic + r) * D + j0 + c4 * 4]);
            *reinterpret_cast<float4*>(&wS[r][c4 * 4]) = t;
        }
        // stage v transposed: vT[c][b] = v_x[b0+b][ic+c]  (64b x 32i, 512 float4 reads)
#pragma unroll
        for (int p = 0; p < 2; ++p) {
            int q  = tid + 256 * p;        // 0..511
            int bq = q >> 3;               // 0..63
            int c4 = q & 7;                // 0..7
            float4 t = *reinterpret_cast<const float4*>(
                &v_x[(size_t)(b0 + bq) * D + ic + c4 * 4]);
            vT[c4 * 4 + 0][bq] = t.x;
            vT[c4 * 4 + 1][bq] = t.y;
            vT[c4 * 4 + 2][bq] = t.z;
            vT[c4 * 4 + 3][bq] = t.w;
        }
        __syncthreads();

#pragma unroll
        for (int ii = 0; ii < IC; ++ii) {
            float4 av  = *reinterpret_cast<const float4*>(&vT[ii][bb]);
            float4 wv0 = *reinterpret_cast<const float4*>(&wS[ii][jj]);
            float4 wv1 = *reinterpret_cast<const float4*>(&wS[ii][jj + 4]);
            float a4[4] = {av.x, av.y, av.z, av.w};
            float w8[8] = {wv0.x, wv0.y, wv0.z, wv0.w, wv1.x, wv1.y, wv1.z, wv1.w};
#pragma unroll
            for (int m = 0; m < 4; ++m)
#pragma unroll
                for (int n = 0; n < 8; ++n)
                    acc[m][n] = fmaf(a4[m], w8[n], acc[m][n]);
        }
        __syncthreads();
    }

    // epilogue: contract with s[b][j], reduce over the 8 jt lanes, atomicAdd
#pragma unroll
    for (int m = 0; m < 4; ++m) {
        const float* srow = s_x + (size_t)(b0 + bb + m) * D + j0 + jj;
        float4 s0 = *reinterpret_cast<const float4*>(srow);
        float4 s1 = *reinterpret_cast<const float4*>(srow + 4);
        float val = acc[m][0]*s0.x + acc[m][1]*s0.y + acc[m][2]*s0.z + acc[m][3]*s0.w
                  + acc[m][4]*s1.x + acc[m][5]*s1.y + acc[m][6]*s1.z + acc[m][7]*s1.w;
        val += __shfl_xor(val, 1);
        val += __shfl_xor(val, 2);
        val += __shfl_xor(val, 4);
        if (jt == 0) {
            atomicAdd(&logits[(b0 + bb + m) * 2 + k], val);
        }
    }
}

// softmax over 2 logits + elementwise blend. One block per batch row.
__global__ __launch_bounds__(192)
void fuse_kernel(const float* __restrict__ v_x,
                 const float* __restrict__ s_x,
                 const float* __restrict__ logits,
                 const float* __restrict__ fc_b,
                 float* __restrict__ out)
{
    const int b = blockIdx.x;
    const float l0 = logits[b * 2 + 0] + fc_b[0];
    const float l1 = logits[b * 2 + 1] + fc_b[1];
    const float mx = fmaxf(l0, l1);
    const float e0 = expf(l0 - mx);
    const float e1 = expf(l1 - mx);
    const float inv = 1.f / (e0 + e1);
    const float wa = e0 * inv;
    const float wb = e1 * inv;

    const int t = threadIdx.x;             // 0..191  (192*4 = 768 floats)
    const float4* v4 = reinterpret_cast<const float4*>(v_x + (size_t)b * D);
    const float4* s4 = reinterpret_cast<const float4*>(s_x + (size_t)b * D);
    float4* o4 = reinterpret_cast<float4*>(out + (size_t)b * D);
    float4 vv = v4[t], ss = s4[t], oo;
    oo.x = wa * vv.x + wb * ss.x;
    oo.y = wa * vv.y + wb * ss.y;
    oo.z = wa * vv.z + wb * ss.z;
    oo.w = wa * vv.w + wb * ss.w;
    o4[t] = oo;
}

extern "C" void kernel_launch(void* const* d_in, const int* in_sizes, int n_in,
                              void* d_out, int out_size, void* d_ws, size_t ws_size,
                              hipStream_t stream) {
    const float* v_x  = (const float*)d_in[0];
    const float* s_x  = (const float*)d_in[1];
    const float* fc_w = (const float*)d_in[2];
    const float* fc_b = (const float*)d_in[3];
    float* out    = (float*)d_out;
    float* logits = (float*)d_ws;          // B*2 floats = 4 KB scratch

    hipMemsetAsync(logits, 0, B * 2 * sizeof(float), stream);

    dim3 g1(D / JTILE, B / BTILE, 2 * ISPLIT);   // 6 x 8 x 16 = 768 blocks
    logits_kernel<<<g1, 256, 0, stream>>>(v_x, s_x, fc_w, logits);

    fuse_kernel<<<B, 192, 0, stream>>>(v_x, s_x, logits, fc_b, out);
}

// Round 2
// 85.784 us; speedup vs baseline: 1.1642x; 1.1642x over previous
//
#include <hip/hip_runtime.h>

#define D 768
#define B 512

// GEMM tiling: logits[b,k] = sum_ij v[b,i] W_k[i,j] s[b,j]
// Block computes a BM x BN output tile of y = v * W_k, dots with s, reduces.
#define BM 128
#define BN 128
#define IC 16                 // i-chunk staged in LDS per iteration
#define ISPLIT 16             // i dimension split across blocks
#define ILEN (D / ISPLIT)     // 48 i's per block (3 chunks of 16)
#define NJT (D / BN)          // 6 j-tiles per k
#define NPART (ISPLIT * NJT)  // 96 partial slots per (b,k)
#define WROW 192              // wS row stride: 16 groups * 12 floats (8 used + 4 pad)
#define VROW 132              // vT row stride: 128 + 4 pad (keeps 16B alignment)

// Writes partial[row][k][gz*NJT+jmod] = sum over this block's (i,j) range.
__global__ __launch_bounds__(256, 4)
void gemm_kernel(const float* __restrict__ v_x,
                 const float* __restrict__ s_x,
                 const float* __restrict__ fc_w,
                 float* __restrict__ partial /* [B][2][NPART] */)
{
    __shared__ float wS[IC * WROW];   // 12.0 KB  [i][group jt][8 floats + 4 pad]
    __shared__ float vT[IC * VROW];   //  8.25 KB [i][b] transposed, padded

    const int tid   = threadIdx.x;
    const int gx    = blockIdx.x;          // 0..11 : j-tile across both k
    const int gy    = blockIdx.y;          // 0..3  : b-tile
    const int gz    = blockIdx.z;          // 0..15 : i-split
    const int k     = gx / NJT;
    const int jmod  = gx % NJT;
    const int jbase = jmod * BN;
    const int b0    = gy * BM;

    const int jt = tid & 15;               // 0..15 : owns 8 j-cols
    const int bt = tid >> 4;               // 0..15 : owns 8 b-rows

    const float* __restrict__ Wk = fc_w + (size_t)k * D * D;

    float acc[8][8];
#pragma unroll
    for (int m = 0; m < 8; ++m)
#pragma unroll
        for (int n = 0; n < 8; ++n) acc[m][n] = 0.f;

    for (int ch = 0; ch < ILEN / IC; ++ch) {
        const int i0 = gz * ILEN + ch * IC;

        // stage W: IC x BN floats = 512 float4, 2 per thread, coalesced rows
#pragma unroll
        for (int p = 0; p < 2; ++p) {
            int q  = tid + 256 * p;        // 0..511
            int r  = q >> 5;               // 0..15
            int c4 = q & 31;               // 0..31
            float4 t = *reinterpret_cast<const float4*>(
                &Wk[(size_t)(i0 + r) * D + jbase + c4 * 4]);
            *reinterpret_cast<float4*>(&wS[r * WROW + (c4 >> 1) * 12 + (c4 & 1) * 4]) = t;
        }
        // stage v transposed: vT[i][b], IC x BM = 512 float4 reads, 2 per thread
#pragma unroll
        for (int p = 0; p < 2; ++p) {
            int q  = tid + 256 * p;        // 0..511
            int bq = q >> 2;               // 0..127
            int c4 = q & 3;                // 0..3
            float4 t = *reinterpret_cast<const float4*>(
                &v_x[(size_t)(b0 + bq) * D + i0 + c4 * 4]);
            vT[(c4 * 4 + 0) * VROW + bq] = t.x;
            vT[(c4 * 4 + 1) * VROW + bq] = t.y;
            vT[(c4 * 4 + 2) * VROW + bq] = t.z;
            vT[(c4 * 4 + 3) * VROW + bq] = t.w;
        }
        __syncthreads();

#pragma unroll
        for (int ii = 0; ii < IC; ++ii) {
            float4 a0 = *reinterpret_cast<const float4*>(&vT[ii * VROW + bt * 8]);
            float4 a1 = *reinterpret_cast<const float4*>(&vT[ii * VROW + bt * 8 + 4]);
            float4 w0 = *reinterpret_cast<const float4*>(&wS[ii * WROW + jt * 12]);
            float4 w1 = *reinterpret_cast<const float4*>(&wS[ii * WROW + jt * 12 + 4]);
            float a8[8] = {a0.x, a0.y, a0.z, a0.w, a1.x, a1.y, a1.z, a1.w};
            float w8[8] = {w0.x, w0.y, w0.z, w0.w, w1.x, w1.y, w1.z, w1.w};
#pragma unroll
            for (int m = 0; m < 8; ++m)
#pragma unroll
                for (int n = 0; n < 8; ++n)
                    acc[m][n] = fmaf(a8[m], w8[n], acc[m][n]);
        }
        __syncthreads();
    }

    // epilogue: dot with s[b][j], reduce over 16 jt lanes, one write per row
#pragma unroll
    for (int m = 0; m < 8; ++m) {
        const int row = b0 + bt * 8 + m;
        const float* sp = s_x + (size_t)row * D + jbase + jt * 8;
        float4 s0 = *reinterpret_cast<const float4*>(sp);
        float4 s1 = *reinterpret_cast<const float4*>(sp + 4);
        float val = acc[m][0]*s0.x + acc[m][1]*s0.y + acc[m][2]*s0.z + acc[m][3]*s0.w
                  + acc[m][4]*s1.x + acc[m][5]*s1.y + acc[m][6]*s1.z + acc[m][7]*s1.w;
        val += __shfl_xor(val, 1);
        val += __shfl_xor(val, 2);
        val += __shfl_xor(val, 4);
        val += __shfl_xor(val, 8);
        if (jt == 0) {
            partial[(size_t)row * (2 * NPART) + k * NPART + gz * NJT + jmod] = val;
        }
    }
}

// Sum partials -> logits -> softmax(2) -> blend. One block per batch row.
__global__ __launch_bounds__(192)
void fuse_kernel(const float* __restrict__ v_x,
                 const float* __restrict__ s_x,
                 const float* __restrict__ partial,
                 const float* __restrict__ fc_b,
                 float* __restrict__ out)
{
    __shared__ float slog[2];
    const int b    = blockIdx.x;
    const int t    = threadIdx.x;          // 0..191
    const int wave = t >> 6;               // 0..2
    const int lane = t & 63;

    if (wave < 2) {
        const float* P = partial + (size_t)b * (2 * NPART) + wave * NPART;
        float val = P[lane];                              // lanes 0..63
        if (lane < NPART - 64) val += P[64 + lane];       // lanes 0..31 add rest
        val += __shfl_xor(val, 1);
        val += __shfl_xor(val, 2);
        val += __shfl_xor(val, 4);
        val += __shfl_xor(val, 8);
        val += __shfl_xor(val, 16);
        val += __shfl_xor(val, 32);
        if (lane == 0) slog[wave] = val + fc_b[wave];
    }
    __syncthreads();

    const float l0 = slog[0], l1 = slog[1];
    const float mx = fmaxf(l0, l1);
    const float e0 = __expf(l0 - mx);
    const float e1 = __expf(l1 - mx);
    const float inv = 1.f / (e0 + e1);
    const float wa = e0 * inv;
    const float wb = e1 * inv;

    const float4* v4 = reinterpret_cast<const float4*>(v_x + (size_t)b * D);
    const float4* s4 = reinterpret_cast<const float4*>(s_x + (size_t)b * D);
    float4* o4 = reinterpret_cast<float4*>((float*)out + (size_t)b * D);
    float4 vv = v4[t], ss = s4[t], oo;
    oo.x = wa * vv.x + wb * ss.x;
    oo.y = wa * vv.y + wb * ss.y;
    oo.z = wa * vv.z + wb * ss.z;
    oo.w = wa * vv.w + wb * ss.w;
    o4[t] = oo;
}

extern "C" void kernel_launch(void* const* d_in, const int* in_sizes, int n_in,
                              void* d_out, int out_size, void* d_ws, size_t ws_size,
                              hipStream_t stream) {
    const float* v_x  = (const float*)d_in[0];
    const float* s_x  = (const float*)d_in[1];
    const float* fc_w = (const float*)d_in[2];
    const float* fc_b = (const float*)d_in[3];
    float* out     = (float*)d_out;
    float* partial = (float*)d_ws;         // B*2*NPART floats = 384 KB

    dim3 g1(2 * NJT, B / BM, ISPLIT);      // 12 x 4 x 16 = 768 blocks, 3/CU
    gemm_kernel<<<g1, 256, 0, stream>>>(v_x, s_x, fc_w, partial);

    fuse_kernel<<<B, 192, 0, stream>>>(v_x, s_x, partial, fc_b, out);
}

// Round 6
// 79.993 us; speedup vs baseline: 1.2484x; 1.0724x over previous
//
#include <hip/hip_runtime.h>

#define D 768
#define B 512

typedef _Float16 half8 __attribute__((ext_vector_type(8)));
typedef float floatx4 __attribute__((ext_vector_type(4)));

// ---------------- prep: WT[cls][j][i] = W[cls][i][j] as f16; v16 = f16(v) ---
// grid: 1152 transpose blocks (2 cls * 24 * 24 tiles of 32x32) + 384 v blocks
__global__ __launch_bounds__(256)
void prep_kernel(const float* __restrict__ v_x,
                 const float* __restrict__ fc_w,
                 _Float16* __restrict__ WT,
                 _Float16* __restrict__ v16)
{
    __shared__ _Float16 tile[32 * 33];
    const int bid = blockIdx.x;
    const int t   = threadIdx.x;

    if (bid < 1152) {
        const int cls = bid / 576;
        const int r2  = bid % 576;
        const int kt  = r2 / 24;        // i-tile
        const int jt  = r2 % 24;        // j-tile
        const float* Wc = fc_w + (size_t)cls * D * D;
        const int r  = t >> 3;          // 0..31
        const int c4 = t & 7;           // 0..7
        float4 f = *reinterpret_cast<const float4*>(
            &Wc[(size_t)(kt * 32 + r) * D + jt * 32 + c4 * 4]);
        tile[r * 33 + c4 * 4 + 0] = (_Float16)f.x;
        tile[r * 33 + c4 * 4 + 1] = (_Float16)f.y;
        tile[r * 33 + c4 * 4 + 2] = (_Float16)f.z;
        tile[r * 33 + c4 * 4 + 3] = (_Float16)f.w;
        __syncthreads();
        alignas(8) _Float16 o[4];
#pragma unroll
        for (int e = 0; e < 4; ++e) o[e] = tile[(c4 * 4 + e) * 33 + r];
        // WT row = cls*768 + (jt*32 + r), cols kt*32 + c4*4 .. +3
        *reinterpret_cast<short4*>(
            &WT[((size_t)cls * D + jt * 32 + r) * D + kt * 32 + c4 * 4]) =
            *reinterpret_cast<short4*>(o);
    } else {
        const int b2 = bid - 1152;       // 0..383, 384*1024 = 393216 = B*D
        const int base = b2 * 1024 + t * 4;
        float4 f = *reinterpret_cast<const float4*>(&v_x[base]);
        alignas(8) _Float16 o[4] = {(_Float16)f.x, (_Float16)f.y,
                                    (_Float16)f.z, (_Float16)f.w};
        *reinterpret_cast<short4*>(&v16[base]) = *reinterpret_cast<short4*>(o);
    }
}

// ---------------- gemm: y = v16 * WT^T (both k-contiguous), fused s-dot -----
#define BM 64
#define BN 128
#define KC 96                 // K-chunk per block (K-split 8)
#define LROW 104              // LDS row stride in f16 (96 + 8 pad = 208 B)
#define NJT 6                 // j-tiles per class
#define NPART 48              // 8 ksplit * 6 jtiles partials per (b, cls)

__global__ __launch_bounds__(256, 3)
void gemm_kernel(const _Float16* __restrict__ v16,
                 const _Float16* __restrict__ WT,
                 const float* __restrict__ s_x,
                 float* __restrict__ partial /* [B][2][NPART] */)
{
    __shared__ _Float16 Alds[BM * LROW];   // 13 KB
    __shared__ _Float16 Blds[BN * LROW];   // 26 KB
    __shared__ float    red[BM * 4];       // 1 KB

    const int tid = threadIdx.x;
    const int jb  = blockIdx.x;            // 0..11 (class = jb/6)
    const int b0  = blockIdx.y * BM;
    const int gz  = blockIdx.z;            // 0..7 k-split
    const int kc0 = gz * KC;

    const int w    = tid >> 6;             // wave 0..3 (owns 32 j-cols)
    const int lane = tid & 63;
    const int li   = lane & 15;
    const int g    = lane >> 4;

    // ---- stage A (64 x 96 f16) : 768 half8 chunks
#pragma unroll
    for (int p = 0; p < 3; ++p) {
        int q   = tid + 256 * p;
        int row = q / 12, ksl = q % 12;
        half8 h = *reinterpret_cast<const half8*>(
            &v16[(size_t)(b0 + row) * D + kc0 + ksl * 8]);
        *reinterpret_cast<half8*>(&Alds[row * LROW + ksl * 8]) = h;
    }
    // ---- stage B (128 x 96 f16) : 1536 half8 chunks
    const _Float16* Wrow = WT + (size_t)jb * BN * D;
#pragma unroll
    for (int p = 0; p < 6; ++p) {
        int q   = tid + 256 * p;
        int row = q / 12, ksl = q % 12;
        half8 h = *reinterpret_cast<const half8*>(
            &Wrow[(size_t)row * D + kc0 + ksl * 8]);
        *reinterpret_cast<half8*>(&Blds[row * LROW + ksl * 8]) = h;
    }
    __syncthreads();

    floatx4 acc[4][2];
#pragma unroll
    for (int m = 0; m < 4; ++m)
#pragma unroll
        for (int n = 0; n < 2; ++n) acc[m][n] = {0.f, 0.f, 0.f, 0.f};

#pragma unroll
    for (int ks = 0; ks < KC / 32; ++ks) {
        half8 a[4], bf[2];
#pragma unroll
        for (int m = 0; m < 4; ++m)
            a[m] = *reinterpret_cast<const half8*>(
                &Alds[(m * 16 + li) * LROW + ks * 32 + g * 8]);
#pragma unroll
        for (int n = 0; n < 2; ++n)
            bf[n] = *reinterpret_cast<const half8*>(
                &Blds[(w * 32 + n * 16 + li) * LROW + ks * 32 + g * 8]);
#pragma unroll
        for (int m = 0; m < 4; ++m)
#pragma unroll
            for (int n = 0; n < 2; ++n)
                acc[m][n] = __builtin_amdgcn_mfma_f32_16x16x32_f16(
                    a[m], bf[n], acc[m][n], 0, 0, 0);
    }

    // ---- epilogue: dot with fp32 s, reduce 16 lanes, then 4 waves via LDS
    const int js  = (jb % NJT) * BN;       // j base within class
    const int cls = jb / NJT;
#pragma unroll
    for (int m = 0; m < 4; ++m)
#pragma unroll
        for (int r = 0; r < 4; ++r) {
            const int row = m * 16 + 4 * g + r;
            const float* sp = s_x + (size_t)(b0 + row) * D + js + w * 32 + li;
            float val = acc[m][0][r] * sp[0] + acc[m][1][r] * sp[16];
            val += __shfl_xor(val, 1);
            val += __shfl_xor(val, 2);
            val += __shfl_xor(val, 4);
            val += __shfl_xor(val, 8);
            if (li == 0) red[row * 4 + w] = val;
        }
    __syncthreads();
    if (tid < BM) {
        float4 rv = *reinterpret_cast<const float4*>(&red[tid * 4]);
        partial[(size_t)(b0 + tid) * (2 * NPART) + cls * NPART + gz * NJT + (jb % NJT)]
            = rv.x + rv.y + rv.z + rv.w;
    }
}

// ---------------- fuse: sum 48 partials -> softmax(2) -> blend --------------
__global__ __launch_bounds__(192)
void fuse_kernel(const float* __restrict__ v_x,
                 const float* __restrict__ s_x,
                 const float* __restrict__ partial,
                 const float* __restrict__ fc_b,
                 float* __restrict__ out)
{
    __shared__ float slog[2];
    const int b    = blockIdx.x;
    const int t    = threadIdx.x;
    const int wave = t >> 6;
    const int lane = t & 63;

    if (wave < 2) {
        const float* P = partial + (size_t)b * (2 * NPART) + wave * NPART;
        float val = (lane < NPART) ? P[lane] : 0.f;
        val += __shfl_xor(val, 1);
        val += __shfl_xor(val, 2);
        val += __shfl_xor(val, 4);
        val += __shfl_xor(val, 8);
        val += __shfl_xor(val, 16);
        val += __shfl_xor(val, 32);
        if (lane == 0) slog[wave] = val + fc_b[wave];
    }
    __syncthreads();

    const float l0 = slog[0], l1 = slog[1];
    const float mx = fmaxf(l0, l1);
    const float e0 = __expf(l0 - mx);
    const float e1 = __expf(l1 - mx);
    const float inv = 1.f / (e0 + e1);
    const float wa = e0 * inv;
    const float wb = e1 * inv;

    const float4* v4 = reinterpret_cast<const float4*>(v_x + (size_t)b * D);
    const float4* s4 = reinterpret_cast<const float4*>(s_x + (size_t)b * D);
    float4* o4 = reinterpret_cast<float4*>((float*)out + (size_t)b * D);
    float4 vv = v4[t], ss = s4[t], oo;
    oo.x = wa * vv.x + wb * ss.x;
    oo.y = wa * vv.y + wb * ss.y;
    oo.z = wa * vv.z + wb * ss.z;
    oo.w = wa * vv.w + wb * ss.w;
    o4[t] = oo;
}

extern "C" void kernel_launch(void* const* d_in, const int* in_sizes, int n_in,
                              void* d_out, int out_size, void* d_ws, size_t ws_size,
                              hipStream_t stream) {
    const float* v_x  = (const float*)d_in[0];
    const float* s_x  = (const float*)d_in[1];
    const float* fc_w = (const float*)d_in[2];
    const float* fc_b = (const float*)d_in[3];
    float* out = (float*)d_out;

    char* ws = (char*)d_ws;
    _Float16* WT  = (_Float16*)(ws);                 // 2*768*768*2 = 2.36 MB
    _Float16* v16 = (_Float16*)(ws + (size_t)(1 << 22));   // 786 KB
    float* partial = (float*)(ws + (size_t)(1 << 23));     // 512*96*4 = 196 KB

    prep_kernel<<<1152 + 384, 256, 0, stream>>>(v_x, fc_w, WT, v16);

    dim3 g1(12, B / BM, 8);                // 768 blocks = 3/CU
    gemm_kernel<<<g1, 256, 0, stream>>>(v16, WT, s_x, partial);

    fuse_kernel<<<B, 192, 0, stream>>>(v_x, s_x, partial, fc_b, out);
}

// Round 7
// 78.235 us; speedup vs baseline: 1.2765x; 1.0225x over previous
//
#include <hip/hip_runtime.h>

#define D 768
#define B 512

typedef _Float16 half8 __attribute__((ext_vector_type(8)));
typedef float floatx4 __attribute__((ext_vector_type(4)));

// ============================================================================
// Reordered contraction: t[b,i] = sum_j s[b,j] * W_k[i,j]   (A = s, B = W_k,
// contraction dim j is row-contiguous in BOTH natural layouts -> no transpose)
// then logits[b,k] = sum_i t[b,i] * v[b,i]  (fused epilogue dot with fp32 v).
// fp32 -> f16 conversion happens during LDS staging. 2 dispatches total.
// ============================================================================
#define BM 64                 // b rows per block
#define BN 128                // i cols per block
#define KC 96                 // j-chunk per block (K-split 8)
#define LROW 104              // LDS row stride in f16 (96 + 8 pad = 208 B)
#define NJT 6                 // i-tiles per class (768/128)
#define NPART 48              // 8 jsplit * 6 itiles partials per (b, cls)

__global__ __launch_bounds__(256, 3)
void gemm_kernel(const _Float16* __restrict__ unused,
                 const float* __restrict__ fc_w,
                 const float* __restrict__ s_x,
                 const float* __restrict__ v_x,
                 float* __restrict__ partial /* [B][2][NPART] */)
{
    __shared__ _Float16 Alds[BM * LROW];   // 13 KB : s tile  [b][j]
    __shared__ _Float16 Blds[BN * LROW];   // 26 KB : W tile  [i][j]
    __shared__ float    red[BM * 4];       // 1 KB

    const int tid = threadIdx.x;
    const int jb  = blockIdx.x;            // 0..11 : cls = jb/6, i-tile = jb%6
    const int b0  = blockIdx.y * BM;
    const int gz  = blockIdx.z;            // 0..7 : j-split
    const int j0  = gz * KC;

    const int cls   = jb / NJT;
    const int it    = jb % NJT;
    const int ibase = it * BN;

    const int w    = tid >> 6;             // wave 0..3 (owns 32 i-cols)
    const int lane = tid & 63;
    const int li   = lane & 15;
    const int g    = lane >> 4;

    // ---- stage A: s[b0..b0+63][j0..j0+95] fp32 -> f16   (1536 float4)
#pragma unroll
    for (int p = 0; p < 6; ++p) {
        int q   = tid + 256 * p;           // 0..1535
        int row = q / 24;                  // 0..63
        int c4  = q % 24;                  // float4 col
        float4 f = *reinterpret_cast<const float4*>(
            &s_x[(size_t)(b0 + row) * D + j0 + c4 * 4]);
        alignas(8) _Float16 h[4] = {(_Float16)f.x, (_Float16)f.y,
                                    (_Float16)f.z, (_Float16)f.w};
        *reinterpret_cast<short4*>(&Alds[row * LROW + c4 * 4]) =
            *reinterpret_cast<short4*>(h);
    }
    // ---- stage B: W_cls[ibase..+127][j0..j0+95] fp32 -> f16   (3072 float4)
    const float* __restrict__ Wc = fc_w + (size_t)cls * D * D;
#pragma unroll
    for (int p = 0; p < 12; ++p) {
        int q   = tid + 256 * p;           // 0..3071
        int row = q / 24;                  // 0..127
        int c4  = q % 24;
        float4 f = *reinterpret_cast<const float4*>(
            &Wc[(size_t)(ibase + row) * D + j0 + c4 * 4]);
        alignas(8) _Float16 h[4] = {(_Float16)f.x, (_Float16)f.y,
                                    (_Float16)f.z, (_Float16)f.w};
        *reinterpret_cast<short4*>(&Blds[row * LROW + c4 * 4]) =
            *reinterpret_cast<short4*>(h);
    }
    __syncthreads();

    floatx4 acc[4][2];
#pragma unroll
    for (int m = 0; m < 4; ++m)
#pragma unroll
        for (int n = 0; n < 2; ++n) acc[m][n] = {0.f, 0.f, 0.f, 0.f};

#pragma unroll
    for (int ks = 0; ks < KC / 32; ++ks) {
        half8 a[4], bf[2];
#pragma unroll
        for (int m = 0; m < 4; ++m)
            a[m] = *reinterpret_cast<const half8*>(
                &Alds[(m * 16 + li) * LROW + ks * 32 + g * 8]);
#pragma unroll
        for (int n = 0; n < 2; ++n)
            bf[n] = *reinterpret_cast<const half8*>(
                &Blds[(w * 32 + n * 16 + li) * LROW + ks * 32 + g * 8]);
#pragma unroll
        for (int m = 0; m < 4; ++m)
#pragma unroll
            for (int n = 0; n < 2; ++n)
                acc[m][n] = __builtin_amdgcn_mfma_f32_16x16x32_f16(
                    a[m], bf[n], acc[m][n], 0, 0, 0);
    }

    // ---- epilogue: dot t[b, i-frag] with fp32 v[b, i], reduce 16 lanes,
    //      then 4 waves via LDS -> one partial per b-row
#pragma unroll
    for (int m = 0; m < 4; ++m)
#pragma unroll
        for (int r = 0; r < 4; ++r) {
            const int row = m * 16 + 4 * g + r;      // b within tile
            const float* vp = v_x + (size_t)(b0 + row) * D + ibase + w * 32 + li;
            float val = acc[m][0][r] * vp[0] + acc[m][1][r] * vp[16];
            val += __shfl_xor(val, 1);
            val += __shfl_xor(val, 2);
            val += __shfl_xor(val, 4);
            val += __shfl_xor(val, 8);
            if (li == 0) red[row * 4 + w] = val;
        }
    __syncthreads();
    if (tid < BM) {
        float4 rv = *reinterpret_cast<const float4*>(&red[tid * 4]);
        partial[(size_t)(b0 + tid) * (2 * NPART) + cls * NPART + gz * NJT + it]
            = rv.x + rv.y + rv.z + rv.w;
    }
}

// ---------------- fuse: sum 48 partials -> softmax(2) -> blend --------------
__global__ __launch_bounds__(192)
void fuse_kernel(const float* __restrict__ v_x,
                 const float* __restrict__ s_x,
                 const float* __restrict__ partial,
                 const float* __restrict__ fc_b,
                 float* __restrict__ out)
{
    __shared__ float slog[2];
    const int b    = blockIdx.x;
    const int t    = threadIdx.x;
    const int wave = t >> 6;
    const int lane = t & 63;

    if (wave < 2) {
        const float* P = partial + (size_t)b * (2 * NPART) + wave * NPART;
        float val = (lane < NPART) ? P[lane] : 0.f;
        val += __shfl_xor(val, 1);
        val += __shfl_xor(val, 2);
        val += __shfl_xor(val, 4);
        val += __shfl_xor(val, 8);
        val += __shfl_xor(val, 16);
        val += __shfl_xor(val, 32);
        if (lane == 0) slog[wave] = val + fc_b[wave];
    }
    __syncthreads();

    const float l0 = slog[0], l1 = slog[1];
    const float mx = fmaxf(l0, l1);
    const float e0 = __expf(l0 - mx);
    const float e1 = __expf(l1 - mx);
    const float inv = 1.f / (e0 + e1);
    const float wa = e0 * inv;
    const float wb = e1 * inv;

    const float4* v4 = reinterpret_cast<const float4*>(v_x + (size_t)b * D);
    const float4* s4 = reinterpret_cast<const float4*>(s_x + (size_t)b * D);
    float4* o4 = reinterpret_cast<float4*>((float*)out + (size_t)b * D);
    float4 vv = v4[t], ss = s4[t], oo;
    oo.x = wa * vv.x + wb * ss.x;
    oo.y = wa * vv.y + wb * ss.y;
    oo.z = wa * vv.z + wb * ss.z;
    oo.w = wa * vv.w + wb * ss.w;
    o4[t] = oo;
}

extern "C" void kernel_launch(void* const* d_in, const int* in_sizes, int n_in,
                              void* d_out, int out_size, void* d_ws, size_t ws_size,
                              hipStream_t stream) {
    const float* v_x  = (const float*)d_in[0];
    const float* s_x  = (const float*)d_in[1];
    const float* fc_w = (const float*)d_in[2];
    const float* fc_b = (const float*)d_in[3];
    float* out = (float*)d_out;

    float* partial = (float*)d_ws;         // 512*96*4 = 196 KB

    dim3 g1(2 * NJT, B / BM, 8);           // 12 x 8 x 8 = 768 blocks, 3/CU
    gemm_kernel<<<g1, 256, 0, stream>>>(nullptr, fc_w, s_x, v_x, partial);

    fuse_kernel<<<B, 192, 0, stream>>>(v_x, s_x, partial, fc_b, out);
}